// Round 12
// baseline (191.475 us; speedup 1.0000x reference)
//
#include <hip/hip_runtime.h>
#include <math.h>

// ---------------------------------------------------------------------------
// 2-layer GCN: out = ReLU(N(x@W1)+b1) -> N(h@W2)+b2, N(.) = D^-1/2 (A+I) D^-1/2
// dinv[src] folded into GEMM epilogue, dinv[dst] into agg epilogue.
// GEMMs: bf16 MFMA (16x16x32), 3-term split precision, fp32 accumulation;
// epilogue writes SLICE-MAJOR bf16 table (NSL slices of 32 feats, 3.2MB <= L2).
// Agg v6: slice-per-XCD + amortized overhead + lean loop (R9/R10) +
//  - nontemporal csr loads (index stream no longer evicts the L2 table)
//  - 2-deep gather pipeline (next iter's gathers in flight during accum)
// CSR via two-level bucket partition; kA/kC use 1024-thread blocks.
// ---------------------------------------------------------------------------

#define CH 8192        // edges per partition block
#define BSH 6          // bucket shift: 64 nodes per bucket
#define NBMAX 1024     // LDS histogram capacity (buckets <= 1024)

typedef __attribute__((ext_vector_type(8))) short short8;
typedef __attribute__((ext_vector_type(4))) float f32x4;

static __device__ __forceinline__ float bflo(unsigned u) { return __uint_as_float(u << 16); }
static __device__ __forceinline__ unsigned short f2bf(float f) {
  unsigned u = __float_as_uint(f);
  return (unsigned short)((u + 0x7fffu + ((u >> 16) & 1u)) >> 16);  // RNE
}
static __device__ __forceinline__ unsigned packbf(float a, float b) {
  return (unsigned)f2bf(a) | ((unsigned)f2bf(b) << 16);
}
static __device__ __forceinline__ void split_bf(float x, unsigned short& h, unsigned short& l) {
  h = f2bf(x);
  float hf = __uint_as_float((unsigned)h << 16);
  l = f2bf(x - hf);
}
// junk-hi unpack: high bf16 added as raw fp32 (low 16 bits = mantissa noise
// <= 2^-8 relative of the addend — same order as bf16 rounding itself).
static __device__ __forceinline__ void accum8(float4& lo, float4& hi, uint4 v) {
  lo.x += bflo(v.x); lo.y += __uint_as_float(v.x);
  lo.z += bflo(v.y); lo.w += __uint_as_float(v.y);
  hi.x += bflo(v.z); hi.y += __uint_as_float(v.z);
  hi.z += bflo(v.w); hi.w += __uint_as_float(v.w);
}
static __device__ __forceinline__ void add4(float4& a, const float4& b) {
  a.x += b.x; a.y += b.y; a.z += b.z; a.w += b.w;
}
static __device__ __forceinline__ void red8(float4& lo, float4& hi, int m) {
  lo.x += __shfl_xor(lo.x, m, 64); lo.y += __shfl_xor(lo.y, m, 64);
  lo.z += __shfl_xor(lo.z, m, 64); lo.w += __shfl_xor(lo.w, m, 64);
  hi.x += __shfl_xor(hi.x, m, 64); hi.y += __shfl_xor(hi.y, m, 64);
  hi.z += __shfl_xor(hi.z, m, 64); hi.w += __shfl_xor(hi.w, m, 64);
}

// ---------------- CSR build ----------------

__global__ __launch_bounds__(1024) void kA_count(const int* __restrict__ dst, int E,
                                                 int NB, int NBLK,
                                                 int* __restrict__ cnt) {
  __shared__ int h[NBMAX];
  int t = threadIdx.x;
  int blk = blockIdx.x;
  for (int i = t; i < NB; i += 1024) h[i] = 0;
  __syncthreads();
  int e0 = blk * CH;
  int e1 = min(E, e0 + CH);
  for (int e = e0 + t; e < e1; e += 1024) atomicAdd(&h[dst[e] >> BSH], 1);
  __syncthreads();
  for (int i = t; i < NB; i += 1024) cnt[i * NBLK + blk] = h[i];
}

__global__ __launch_bounds__(1024) void k_scanA(const int* __restrict__ in, int M,
                                                int* __restrict__ out,
                                                int* __restrict__ bsum) {
  __shared__ int sd[1024];
  int tid = threadIdx.x;
  int i = blockIdx.x * 1024 + tid;
  int v = (i < M) ? in[i] : 0;
  sd[tid] = v;
  __syncthreads();
  for (int off = 1; off < 1024; off <<= 1) {
    int t = (tid >= off) ? sd[tid - off] : 0;
    __syncthreads();
    sd[tid] += t;
    __syncthreads();
  }
  if (i < M) out[i] = sd[tid] - v;  // block-local exclusive
  if (tid == 1023) bsum[blockIdx.x] = sd[1023];  // raw block totals
}

// exclusive scan of bsum (<=256 entries) into ex[]; callable from wide blocks
static __device__ __forceinline__ void scan_bsum_wide(const int* __restrict__ bsum,
                                                      int nsb, int t,
                                                      int* ex, int* sd) {
  int v = 0;
  if (t < 256) {
    v = (t < nsb) ? bsum[t] : 0;
    ex[t] = v;
    sd[t] = v;
  }
  __syncthreads();
  for (int off = 1; off < 256; off <<= 1) {
    int u = (t < 256 && t >= off) ? sd[t - off] : 0;
    __syncthreads();
    if (t < 256) sd[t] += u;
    __syncthreads();
  }
  if (t < 256) ex[t] = sd[t] - ex[t];  // exclusive
  __syncthreads();
}

__global__ __launch_bounds__(1024) void kC_scatter(const int* __restrict__ src,
                                                   const int* __restrict__ dst, int E,
                                                   int NB, int NBLK, int NSB,
                                                   const int* __restrict__ pos,
                                                   const int* __restrict__ bsum,
                                                   int* __restrict__ ppack) {
  __shared__ int lcur[NBMAX];
  __shared__ int ex[256];
  __shared__ int sd[256];
  int t = threadIdx.x;
  int blk = blockIdx.x;
  scan_bsum_wide(bsum, NSB, t, ex, sd);
  for (int i = t; i < NB; i += 1024) {
    int f = i * NBLK + blk;
    lcur[i] = pos[f] + ex[f >> 10];
  }
  __syncthreads();
  int e0 = blk * CH;
  int e1 = min(E, e0 + CH);
  for (int e = e0 + t; e < e1; e += 1024) {
    int d = dst[e];
    int p = atomicAdd(&lcur[d >> BSH], 1);
    ppack[p] = (src[e] << BSH) | (d & ((1 << BSH) - 1));
  }
}

__global__ __launch_bounds__(256) void kD_build(const int* __restrict__ ppack,
                                                const int* __restrict__ pos,
                                                const int* __restrict__ bsum,
                                                int N, int E, int NB, int NBLK, int NSB,
                                                int* __restrict__ csr,
                                                int* __restrict__ deg,
                                                int* __restrict__ offs,
                                                float* __restrict__ dinv) {
  __shared__ int ex[256];
  __shared__ int sd[256];
  __shared__ int ldeg[64];
  __shared__ int lsc[64];
  __shared__ int lcur[64];
  int t = threadIdx.x;
  int q = blockIdx.x;
  scan_bsum_wide(bsum, NSB, t, ex, sd);
  int node_lo = q << BSH;
  int f0 = q * NBLK;
  int base = pos[f0] + ex[f0 >> 10];
  int end;
  if (q == NB - 1) end = E;
  else {
    int f1 = (q + 1) * NBLK;
    end = pos[f1] + ex[f1 >> 10];
  }
  if (t < 64) ldeg[t] = 0;
  __syncthreads();
  for (int e = base + t; e < end; e += 256)
    atomicAdd(&ldeg[ppack[e] & 63], 1);
  __syncthreads();
  int v = (t < 64) ? ldeg[t] : 0;
  if (t < 64) lsc[t] = v;
  __syncthreads();
  for (int off = 1; off < 64; off <<= 1) {
    int tmp = (t < 64 && t >= off) ? lsc[t - off] : 0;
    __syncthreads();
    if (t < 64) lsc[t] += tmp;
    __syncthreads();
  }
  if (t < 64) {
    int exn = lsc[t] - v;
    lcur[t] = exn;
    int g = node_lo + t;
    if (g < N) {
      deg[g] = v;
      offs[g] = base + exn;
      dinv[g] = rsqrtf((float)(v + 1));  // +1 self loop
    }
  }
  __syncthreads();
  for (int e = base + t; e < end; e += 256) {
    int pk = ppack[e];
    int p = atomicAdd(&lcur[pk & 63], 1);
    csr[base + p] = pk >> BSH;
  }
}

// ---------------- MFMA GEMM -> sliced bf16 table ---------------------------
__global__ __launch_bounds__(256) void k_gemm_mfma(
    const float* __restrict__ X, const float* __restrict__ W,
    const float* __restrict__ dinv, unsigned short* __restrict__ T,
    int Mreal, int Mpad, int NC) {
  __shared__ short lds[4352 * 2 + 8704 * 2];
  short* Xh = lds;
  short* Xl = lds + 4352;
  short* Wh = lds + 8704;
  short* Wl = lds + 8704 + 8704;
  const int t = threadIdx.x;
  const int bm = blockIdx.x * 32;
  const int bn = blockIdx.y * 64;

  #pragma unroll
  for (int i = 0; i < 4; ++i) {
    int slot = t + i * 256;
    int row = slot >> 5;
    int q = slot & 31;
    int rr = bm + row;
    if (rr >= Mreal) rr = Mreal - 1;
    float4 v = *(const float4*)(X + (size_t)rr * 128 + q * 4);
    unsigned short h0, l0, h1, l1, h2, l2, h3, l3;
    split_bf(v.x, h0, l0); split_bf(v.y, h1, l1);
    split_bf(v.z, h2, l2); split_bf(v.w, h3, l3);
    int idx = row * 136 + q * 4;
    *(uint2*)&Xh[idx] = make_uint2((unsigned)h0 | ((unsigned)h1 << 16),
                                   (unsigned)h2 | ((unsigned)h3 << 16));
    *(uint2*)&Xl[idx] = make_uint2((unsigned)l0 | ((unsigned)l1 << 16),
                                   (unsigned)l2 | ((unsigned)l3 << 16));
  }
  #pragma unroll
  for (int i = 0; i < 8; ++i) {
    int slot = t + i * 256;
    int k = slot >> 4;
    int q = slot & 15;
    float4 v = *(const float4*)(W + (size_t)k * NC + bn + q * 4);
    unsigned short h, l;
    split_bf(v.x, h, l); Wh[(q * 4 + 0) * 136 + k] = h; Wl[(q * 4 + 0) * 136 + k] = l;
    split_bf(v.y, h, l); Wh[(q * 4 + 1) * 136 + k] = h; Wl[(q * 4 + 1) * 136 + k] = l;
    split_bf(v.z, h, l); Wh[(q * 4 + 2) * 136 + k] = h; Wl[(q * 4 + 2) * 136 + k] = l;
    split_bf(v.w, h, l); Wh[(q * 4 + 3) * 136 + k] = h; Wl[(q * 4 + 3) * 136 + k] = l;
  }
  __syncthreads();

  const int lane = t & 63;
  const int wid = t >> 6;
  const int wm = wid >> 1;
  const int wn = wid & 1;
  const int lm = lane & 15;
  const int kg = lane >> 4;
  f32x4 acc[2] = {{0.f, 0.f, 0.f, 0.f}, {0.f, 0.f, 0.f, 0.f}};
  #pragma unroll
  for (int ks = 0; ks < 4; ++ks) {
    int kof = ks * 32 + kg * 8;
    short8 ah = *(const short8*)&Xh[(wm * 16 + lm) * 136 + kof];
    short8 al = *(const short8*)&Xl[(wm * 16 + lm) * 136 + kof];
    #pragma unroll
    for (int nt = 0; nt < 2; ++nt) {
      int nrow = (wn * 32 + nt * 16 + lm) * 136 + kof;
      short8 bh = *(const short8*)&Wh[nrow];
      short8 bl = *(const short8*)&Wl[nrow];
      acc[nt] = __builtin_amdgcn_mfma_f32_16x16x32_bf16(ah, bh, acc[nt], 0, 0, 0);
      acc[nt] = __builtin_amdgcn_mfma_f32_16x16x32_bf16(al, bh, acc[nt], 0, 0, 0);
      acc[nt] = __builtin_amdgcn_mfma_f32_16x16x32_bf16(ah, bl, acc[nt], 0, 0, 0);
    }
  }
  __syncthreads();
  float* rep = (float*)lds;  // [32][68]
  #pragma unroll
  for (int nt = 0; nt < 2; ++nt)
    #pragma unroll
    for (int i = 0; i < 4; ++i)
      rep[(wm * 16 + kg * 4 + i) * 68 + wn * 32 + nt * 16 + lm] = acc[nt][i];
  __syncthreads();
  #pragma unroll
  for (int it = 0; it < 2; ++it) {
    int slot = t + it * 256;
    int lrow = slot >> 4;
    int q = slot & 15;
    int gr = bm + lrow;
    if (gr < Mpad) {
      float dn = (gr < Mreal) ? dinv[gr] : 0.f;
      const float* rp = rep + lrow * 68 + q * 4;
      int f0 = bn + q * 4;
      int sel = f0 >> 5;  // slice
      uint2 o = make_uint2(packbf(rp[0] * dn, rp[1] * dn),
                           packbf(rp[2] * dn, rp[3] * dn));
      *(uint2*)(T + (size_t)sel * Mpad * 32 + (size_t)gr * 32 + (f0 & 31)) = o;
    }
  }
}

// ---------------- Sliced aggregation v6 ------------------------------------
// 16-lane group per node (4 nodes/wave); es = edge quad, fl = 16B piece of
// the 64B slice row. 2-deep gather pipeline: iter k+1's gathers issue before
// iter k's accumulate; index stream loaded nontemporally (keeps table in L2);
// tail reuses the already-loaded next index set.
template <int NSL, int NC, bool RELU>
__global__ __launch_bounds__(256) void k_agg_v6(
    const unsigned short* __restrict__ T, const int* __restrict__ csr,
    const int* __restrict__ offs, const int* __restrict__ deg,
    const float* __restrict__ dinv, const float* __restrict__ bias,
    float* __restrict__ Out, int N, int Mpad) {
  const int lane = threadIdx.x & 63;
  const int wave = threadIdx.x >> 6;
  const int P = blockIdx.x;
  const int xcd = P & 7;
  const int slice = xcd & (NSL - 1);
  const int chunk = (P >> 3) * (8 / NSL) + (xcd / NSL);
  const int grp = lane >> 4;       // node group within wave (4 nodes/wave)
  const int es = (lane >> 2) & 3;  // edge quad index
  const int fl = lane & 3;         // 16B piece of the 64B slice row
  const int node = chunk * 16 + wave * 4 + grp;
  const char* Tb = (const char*)(T + (size_t)slice * Mpad * 32);
  const bool valid = node < N;
  int start = 0, cnt = 0;
  if (valid) { start = offs[node]; cnt = deg[node]; }
  const unsigned loff = (unsigned)fl << 4;
  float4 lo0 = {0,0,0,0}, hi0 = {0,0,0,0}, lo1 = {0,0,0,0}, hi1 = {0,0,0,0};
  float4 lo2 = {0,0,0,0}, hi2 = {0,0,0,0}, lo3 = {0,0,0,0}, hi3 = {0,0,0,0};
  {  // self loop: only es==0 lanes add the node's own row; others hit zeros
    int s = (es == 0 && valid) ? node : N;
    uint4 v = *(const uint4*)(Tb + (((unsigned)s << 6) + loff));
    accum8(lo0, hi0, v);
  }
  const int nfull = cnt >> 4;
  const int rem = cnt & 15;
  const int qb = es * 4;
  int bidx = start + qb;
  if (nfull > 0) {
    // iter-0 indices + gathers
    int a0 = __builtin_nontemporal_load(csr + bidx + 0);
    int a1 = __builtin_nontemporal_load(csr + bidx + 1);
    int a2 = __builtin_nontemporal_load(csr + bidx + 2);
    int a3 = __builtin_nontemporal_load(csr + bidx + 3);
    uint4 p0 = *(const uint4*)(Tb + (((unsigned)a0 << 6) + loff));
    uint4 p1 = *(const uint4*)(Tb + (((unsigned)a1 << 6) + loff));
    uint4 p2 = *(const uint4*)(Tb + (((unsigned)a2 << 6) + loff));
    uint4 p3 = *(const uint4*)(Tb + (((unsigned)a3 << 6) + loff));
    bidx += 16;
    // iter-1 indices (raw; csr pad covers over-read — doubles as tail idx)
    int b0 = __builtin_nontemporal_load(csr + bidx + 0);
    int b1 = __builtin_nontemporal_load(csr + bidx + 1);
    int b2 = __builtin_nontemporal_load(csr + bidx + 2);
    int b3 = __builtin_nontemporal_load(csr + bidx + 3);
    for (int it = 1; it < nfull; ++it) {
      // issue iter-it gathers (indices already resident)
      uint4 q0 = *(const uint4*)(Tb + (((unsigned)b0 << 6) + loff));
      uint4 q1 = *(const uint4*)(Tb + (((unsigned)b1 << 6) + loff));
      uint4 q2 = *(const uint4*)(Tb + (((unsigned)b2 << 6) + loff));
      uint4 q3 = *(const uint4*)(Tb + (((unsigned)b3 << 6) + loff));
      bidx += 16;
      b0 = __builtin_nontemporal_load(csr + bidx + 0);
      b1 = __builtin_nontemporal_load(csr + bidx + 1);
      b2 = __builtin_nontemporal_load(csr + bidx + 2);
      b3 = __builtin_nontemporal_load(csr + bidx + 3);
      // accumulate iter-(it-1) while iter-it gathers are in flight
      accum8(lo0, hi0, p0); accum8(lo1, hi1, p1);
      accum8(lo2, hi2, p2); accum8(lo3, hi3, p3);
      p0 = q0; p1 = q1; p2 = q2; p3 = q3;
    }
    if (rem) {  // tail: b* already hold the tail indices
      int s0 = (qb + 0 < rem) ? b0 : N;
      int s1 = (qb + 1 < rem) ? b1 : N;
      int s2 = (qb + 2 < rem) ? b2 : N;
      int s3 = (qb + 3 < rem) ? b3 : N;
      uint4 q0 = *(const uint4*)(Tb + (((unsigned)s0 << 6) + loff));
      uint4 q1 = *(const uint4*)(Tb + (((unsigned)s1 << 6) + loff));
      uint4 q2 = *(const uint4*)(Tb + (((unsigned)s2 << 6) + loff));
      uint4 q3 = *(const uint4*)(Tb + (((unsigned)s3 << 6) + loff));
      accum8(lo0, hi0, p0); accum8(lo1, hi1, p1);
      accum8(lo2, hi2, p2); accum8(lo3, hi3, p3);
      accum8(lo0, hi0, q0); accum8(lo1, hi1, q1);
      accum8(lo2, hi2, q2); accum8(lo3, hi3, q3);
    } else {
      accum8(lo0, hi0, p0); accum8(lo1, hi1, p1);
      accum8(lo2, hi2, p2); accum8(lo3, hi3, p3);
    }
  } else if (rem) {  // tiny node: single predicated batch
    int a0 = __builtin_nontemporal_load(csr + bidx + 0);
    int a1 = __builtin_nontemporal_load(csr + bidx + 1);
    int a2 = __builtin_nontemporal_load(csr + bidx + 2);
    int a3 = __builtin_nontemporal_load(csr + bidx + 3);
    int s0 = (qb + 0 < rem) ? a0 : N;
    int s1 = (qb + 1 < rem) ? a1 : N;
    int s2 = (qb + 2 < rem) ? a2 : N;
    int s3 = (qb + 3 < rem) ? a3 : N;
    uint4 q0 = *(const uint4*)(Tb + (((unsigned)s0 << 6) + loff));
    uint4 q1 = *(const uint4*)(Tb + (((unsigned)s1 << 6) + loff));
    uint4 q2 = *(const uint4*)(Tb + (((unsigned)s2 << 6) + loff));
    uint4 q3 = *(const uint4*)(Tb + (((unsigned)s3 << 6) + loff));
    accum8(lo0, hi0, q0); accum8(lo1, hi1, q1);
    accum8(lo2, hi2, q2); accum8(lo3, hi3, q3);
  }
  add4(lo0, lo1); add4(hi0, hi1);
  add4(lo2, lo3); add4(hi2, hi3);
  add4(lo0, lo2); add4(hi0, hi2);
  red8(lo0, hi0, 4);   // combine es (lane bits 2-3)
  red8(lo0, hi0, 8);
  if (es == 0 && valid) {
    float dn = dinv[node];
    int fb = slice * 32 + fl * 8;
    float4 bb0 = *(const float4*)(bias + fb);
    float4 bb1 = *(const float4*)(bias + fb + 4);
    float4 o0, o1;
    o0.x = fmaf(lo0.x, dn, bb0.x); o0.y = fmaf(lo0.y, dn, bb0.y);
    o0.z = fmaf(lo0.z, dn, bb0.z); o0.w = fmaf(lo0.w, dn, bb0.w);
    o1.x = fmaf(hi0.x, dn, bb1.x); o1.y = fmaf(hi0.y, dn, bb1.y);
    o1.z = fmaf(hi0.z, dn, bb1.z); o1.w = fmaf(hi0.w, dn, bb1.w);
    if (RELU) {
      o0.x = fmaxf(o0.x, 0.f); o0.y = fmaxf(o0.y, 0.f);
      o0.z = fmaxf(o0.z, 0.f); o0.w = fmaxf(o0.w, 0.f);
      o1.x = fmaxf(o1.x, 0.f); o1.y = fmaxf(o1.y, 0.f);
      o1.z = fmaxf(o1.z, 0.f); o1.w = fmaxf(o1.w, 0.f);
    }
    *(float4*)(Out + (size_t)node * NC + fb) = o0;
    *(float4*)(Out + (size_t)node * NC + fb + 4) = o1;
  }
}

extern "C" void kernel_launch(void* const* d_in, const int* in_sizes, int n_in,
                              void* d_out, int out_size, void* d_ws, size_t ws_size,
                              hipStream_t stream) {
  const float* x = (const float*)d_in[0];
  const int* ei = (const int*)d_in[1];
  const float* W1 = (const float*)d_in[2];
  const float* b1 = (const float*)d_in[3];
  const float* W2 = (const float*)d_in[4];
  const float* b2 = (const float*)d_in[5];
  float* out = (float*)d_out;

  const int N = in_sizes[0] / 128;  // 50000
  const int E = in_sizes[1] / 2;    // 1600000
  const int* src = ei;
  const int* dst = ei + E;

  const int NB = (N + (1 << BSH) - 1) >> BSH;  // buckets (782)
  const int NBLK = (E + CH - 1) / CH;          // partition blocks (196)
  const int M = NB * NBLK;                     // count-table entries
  const int NSB = (M + 1023) / 1024;           // scan blocks (<=256)

  // workspace layout (aliased; tables live in A region, packed pairs in B)
  float* A = (float*)d_ws;                 // N*128 floats region
  float* B = A + (size_t)N * 128;          // N*128 floats region
  int* csr = (int*)(B + (size_t)N * 128);  // E ints (+128 pad for raw prefetch)
  int* deg = csr + E + 128;                // N
  int* offs = deg + N;                     // N
  float* dinv = (float*)(offs + N);        // N
  int* cnt = (int*)A;                      // M (alias A)
  int* pos = cnt + M;                      // M (alias A)
  int* bsum = pos + M;                     // <=256 (alias A)
  int* ppack = (int*)B;                    // E packed pairs (alias B)
  unsigned short* T1 = (unsigned short*)A;  // 4 slices x Mpad x 32 bf16
  unsigned short* T2 = (unsigned short*)A;  // 2 slices x Mpad x 32 bf16

  kA_count<<<NBLK, 1024, 0, stream>>>(dst, E, NB, NBLK, cnt);
  k_scanA<<<NSB, 1024, 0, stream>>>(cnt, M, pos, bsum);
  kC_scatter<<<NBLK, 1024, 0, stream>>>(src, dst, E, NB, NBLK, NSB, pos, bsum, ppack);
  kD_build<<<NB, 256, 0, stream>>>(ppack, pos, bsum, N, E, NB, NBLK, NSB,
                                   csr, deg, offs, dinv);

  const int Mpad = N + 1;
  const int MT = (Mpad + 31) / 32;   // m-blocks (covers dummy row N)
  const int NC16 = (N + 15) / 16;    // node chunks of 16

  dim3 g1(MT, 2);
  k_gemm_mfma<<<g1, 256, 0, stream>>>(x, W1, dinv, T1, N, Mpad, 128);
  {  // layer-1 agg: 4 slices (2 XCDs each)
    int grid = 8 * ((NC16 + 1) / 2);
    k_agg_v6<4, 128, true><<<grid, 256, 0, stream>>>(T1, csr, offs, deg,
                                                     dinv, b1, B, N, Mpad);
  }
  dim3 g2(MT, 1);
  k_gemm_mfma<<<g2, 256, 0, stream>>>(B, W2, dinv, T2, N, Mpad, 64);
  {  // layer-2 agg: 2 slices (4 XCDs each)
    int grid = 8 * ((NC16 + 3) / 4);
    k_agg_v6<2, 64, false><<<grid, 256, 0, stream>>>(T2, csr, offs, deg,
                                                     dinv, b2, out, N, Mpad);
  }
}

// Round 13
// 159.999 us; speedup vs baseline: 1.1967x; 1.1967x over previous
//
#include <hip/hip_runtime.h>
#include <math.h>

// ---------------------------------------------------------------------------
// 2-layer GCN: out = ReLU(N(x@W1)+b1) -> N(h@W2)+b2, N(.) = D^-1/2 (A+I) D^-1/2
// dinv[src] folded into GEMM epilogue, dinv[dst] into agg epilogue.
// GEMMs: bf16 MFMA (16x16x32), 3-term split precision, fp32 accumulation;
// epilogue writes SLICE-MAJOR bf16 table (NSL slices of 32 feats, 3.2MB <= L2).
// Agg v4 (best measured): slice-per-XCD (FETCH 155->35MB) + amortized
// overhead: 16-lane group per node (4 nodes/wave), 4 lanes x 16B per 64B
// slice row, 4 edge slots per lane, index prefetch + dummy-row predication.
// CSR via two-level bucket partition; kA/kC use 1024-thread blocks.
// ---------------------------------------------------------------------------

#define CH 8192        // edges per partition block
#define BSH 6          // bucket shift: 64 nodes per bucket
#define NBMAX 1024     // LDS histogram capacity (buckets <= 1024)

typedef __attribute__((ext_vector_type(8))) short short8;
typedef __attribute__((ext_vector_type(4))) float f32x4;

static __device__ __forceinline__ float bflo(unsigned u) { return __uint_as_float(u << 16); }
static __device__ __forceinline__ float bfhi(unsigned u) { return __uint_as_float(u & 0xffff0000u); }
static __device__ __forceinline__ unsigned short f2bf(float f) {
  unsigned u = __float_as_uint(f);
  return (unsigned short)((u + 0x7fffu + ((u >> 16) & 1u)) >> 16);  // RNE
}
static __device__ __forceinline__ unsigned packbf(float a, float b) {
  return (unsigned)f2bf(a) | ((unsigned)f2bf(b) << 16);
}
static __device__ __forceinline__ void split_bf(float x, unsigned short& h, unsigned short& l) {
  h = f2bf(x);
  float hf = __uint_as_float((unsigned)h << 16);
  l = f2bf(x - hf);
}
static __device__ __forceinline__ void accum8(float4& lo, float4& hi, uint4 v) {
  lo.x += bflo(v.x); lo.y += bfhi(v.x);
  lo.z += bflo(v.y); lo.w += bfhi(v.y);
  hi.x += bflo(v.z); hi.y += bfhi(v.z);
  hi.z += bflo(v.w); hi.w += bfhi(v.w);
}
static __device__ __forceinline__ void add4(float4& a, const float4& b) {
  a.x += b.x; a.y += b.y; a.z += b.z; a.w += b.w;
}
static __device__ __forceinline__ void red8(float4& lo, float4& hi, int m) {
  lo.x += __shfl_xor(lo.x, m, 64); lo.y += __shfl_xor(lo.y, m, 64);
  lo.z += __shfl_xor(lo.z, m, 64); lo.w += __shfl_xor(lo.w, m, 64);
  hi.x += __shfl_xor(hi.x, m, 64); hi.y += __shfl_xor(hi.y, m, 64);
  hi.z += __shfl_xor(hi.z, m, 64); hi.w += __shfl_xor(hi.w, m, 64);
}

// ---------------- CSR build ----------------

__global__ __launch_bounds__(1024) void kA_count(const int* __restrict__ dst, int E,
                                                 int NB, int NBLK,
                                                 int* __restrict__ cnt) {
  __shared__ int h[NBMAX];
  int t = threadIdx.x;
  int blk = blockIdx.x;
  for (int i = t; i < NB; i += 1024) h[i] = 0;
  __syncthreads();
  int e0 = blk * CH;
  int e1 = min(E, e0 + CH);
  for (int e = e0 + t; e < e1; e += 1024) atomicAdd(&h[dst[e] >> BSH], 1);
  __syncthreads();
  for (int i = t; i < NB; i += 1024) cnt[i * NBLK + blk] = h[i];
}

__global__ __launch_bounds__(1024) void k_scanA(const int* __restrict__ in, int M,
                                                int* __restrict__ out,
                                                int* __restrict__ bsum) {
  __shared__ int sd[1024];
  int tid = threadIdx.x;
  int i = blockIdx.x * 1024 + tid;
  int v = (i < M) ? in[i] : 0;
  sd[tid] = v;
  __syncthreads();
  for (int off = 1; off < 1024; off <<= 1) {
    int t = (tid >= off) ? sd[tid - off] : 0;
    __syncthreads();
    sd[tid] += t;
    __syncthreads();
  }
  if (i < M) out[i] = sd[tid] - v;  // block-local exclusive
  if (tid == 1023) bsum[blockIdx.x] = sd[1023];  // raw block totals
}

// exclusive scan of bsum (<=256 entries) into ex[]; callable from wide blocks
// (only t<256 participate in scan math; all threads hit the barriers).
static __device__ __forceinline__ void scan_bsum_wide(const int* __restrict__ bsum,
                                                      int nsb, int t,
                                                      int* ex, int* sd) {
  int v = 0;
  if (t < 256) {
    v = (t < nsb) ? bsum[t] : 0;
    ex[t] = v;
    sd[t] = v;
  }
  __syncthreads();
  for (int off = 1; off < 256; off <<= 1) {
    int u = (t < 256 && t >= off) ? sd[t - off] : 0;
    __syncthreads();
    if (t < 256) sd[t] += u;
    __syncthreads();
  }
  if (t < 256) ex[t] = sd[t] - ex[t];  // exclusive
  __syncthreads();
}

__global__ __launch_bounds__(1024) void kC_scatter(const int* __restrict__ src,
                                                   const int* __restrict__ dst, int E,
                                                   int NB, int NBLK, int NSB,
                                                   const int* __restrict__ pos,
                                                   const int* __restrict__ bsum,
                                                   int* __restrict__ ppack) {
  __shared__ int lcur[NBMAX];
  __shared__ int ex[256];
  __shared__ int sd[256];
  int t = threadIdx.x;
  int blk = blockIdx.x;
  scan_bsum_wide(bsum, NSB, t, ex, sd);
  for (int i = t; i < NB; i += 1024) {
    int f = i * NBLK + blk;
    lcur[i] = pos[f] + ex[f >> 10];
  }
  __syncthreads();
  int e0 = blk * CH;
  int e1 = min(E, e0 + CH);
  for (int e = e0 + t; e < e1; e += 1024) {
    int d = dst[e];
    int p = atomicAdd(&lcur[d >> BSH], 1);
    ppack[p] = (src[e] << BSH) | (d & ((1 << BSH) - 1));
  }
}

__global__ __launch_bounds__(256) void kD_build(const int* __restrict__ ppack,
                                                const int* __restrict__ pos,
                                                const int* __restrict__ bsum,
                                                int N, int E, int NB, int NBLK, int NSB,
                                                int* __restrict__ csr,
                                                int* __restrict__ deg,
                                                int* __restrict__ offs,
                                                float* __restrict__ dinv) {
  __shared__ int ex[256];
  __shared__ int sd[256];
  __shared__ int ldeg[64];
  __shared__ int lsc[64];
  __shared__ int lcur[64];
  int t = threadIdx.x;
  int q = blockIdx.x;
  scan_bsum_wide(bsum, NSB, t, ex, sd);
  int node_lo = q << BSH;
  int f0 = q * NBLK;
  int base = pos[f0] + ex[f0 >> 10];
  int end;
  if (q == NB - 1) end = E;
  else {
    int f1 = (q + 1) * NBLK;
    end = pos[f1] + ex[f1 >> 10];
  }
  if (t < 64) ldeg[t] = 0;
  __syncthreads();
  for (int e = base + t; e < end; e += 256)
    atomicAdd(&ldeg[ppack[e] & 63], 1);
  __syncthreads();
  int v = (t < 64) ? ldeg[t] : 0;
  if (t < 64) lsc[t] = v;
  __syncthreads();
  for (int off = 1; off < 64; off <<= 1) {
    int tmp = (t < 64 && t >= off) ? lsc[t - off] : 0;
    __syncthreads();
    if (t < 64) lsc[t] += tmp;
    __syncthreads();
  }
  if (t < 64) {
    int exn = lsc[t] - v;
    lcur[t] = exn;
    int g = node_lo + t;
    if (g < N) {
      deg[g] = v;
      offs[g] = base + exn;
      dinv[g] = rsqrtf((float)(v + 1));  // +1 self loop
    }
  }
  __syncthreads();
  for (int e = base + t; e < end; e += 256) {
    int pk = ppack[e];
    int p = atomicAdd(&lcur[pk & 63], 1);
    csr[base + p] = pk >> BSH;
  }
}

// ---------------- MFMA GEMM -> sliced bf16 table ---------------------------
// T laid out as slices of 32 feats: slice sel at offset sel*Mpad*32 shorts.
__global__ __launch_bounds__(256) void k_gemm_mfma(
    const float* __restrict__ X, const float* __restrict__ W,
    const float* __restrict__ dinv, unsigned short* __restrict__ T,
    int Mreal, int Mpad, int NC) {
  __shared__ short lds[4352 * 2 + 8704 * 2];
  short* Xh = lds;
  short* Xl = lds + 4352;
  short* Wh = lds + 8704;
  short* Wl = lds + 8704 + 8704;
  const int t = threadIdx.x;
  const int bm = blockIdx.x * 32;
  const int bn = blockIdx.y * 64;

  #pragma unroll
  for (int i = 0; i < 4; ++i) {
    int slot = t + i * 256;
    int row = slot >> 5;
    int q = slot & 31;
    int rr = bm + row;
    if (rr >= Mreal) rr = Mreal - 1;
    float4 v = *(const float4*)(X + (size_t)rr * 128 + q * 4);
    unsigned short h0, l0, h1, l1, h2, l2, h3, l3;
    split_bf(v.x, h0, l0); split_bf(v.y, h1, l1);
    split_bf(v.z, h2, l2); split_bf(v.w, h3, l3);
    int idx = row * 136 + q * 4;
    *(uint2*)&Xh[idx] = make_uint2((unsigned)h0 | ((unsigned)h1 << 16),
                                   (unsigned)h2 | ((unsigned)h3 << 16));
    *(uint2*)&Xl[idx] = make_uint2((unsigned)l0 | ((unsigned)l1 << 16),
                                   (unsigned)l2 | ((unsigned)l3 << 16));
  }
  #pragma unroll
  for (int i = 0; i < 8; ++i) {
    int slot = t + i * 256;
    int k = slot >> 4;
    int q = slot & 15;
    float4 v = *(const float4*)(W + (size_t)k * NC + bn + q * 4);
    unsigned short h, l;
    split_bf(v.x, h, l); Wh[(q * 4 + 0) * 136 + k] = h; Wl[(q * 4 + 0) * 136 + k] = l;
    split_bf(v.y, h, l); Wh[(q * 4 + 1) * 136 + k] = h; Wl[(q * 4 + 1) * 136 + k] = l;
    split_bf(v.z, h, l); Wh[(q * 4 + 2) * 136 + k] = h; Wl[(q * 4 + 2) * 136 + k] = l;
    split_bf(v.w, h, l); Wh[(q * 4 + 3) * 136 + k] = h; Wl[(q * 4 + 3) * 136 + k] = l;
  }
  __syncthreads();

  const int lane = t & 63;
  const int wid = t >> 6;
  const int wm = wid >> 1;
  const int wn = wid & 1;
  const int lm = lane & 15;
  const int kg = lane >> 4;
  f32x4 acc[2] = {{0.f, 0.f, 0.f, 0.f}, {0.f, 0.f, 0.f, 0.f}};
  #pragma unroll
  for (int ks = 0; ks < 4; ++ks) {
    int kof = ks * 32 + kg * 8;
    short8 ah = *(const short8*)&Xh[(wm * 16 + lm) * 136 + kof];
    short8 al = *(const short8*)&Xl[(wm * 16 + lm) * 136 + kof];
    #pragma unroll
    for (int nt = 0; nt < 2; ++nt) {
      int nrow = (wn * 32 + nt * 16 + lm) * 136 + kof;
      short8 bh = *(const short8*)&Wh[nrow];
      short8 bl = *(const short8*)&Wl[nrow];
      acc[nt] = __builtin_amdgcn_mfma_f32_16x16x32_bf16(ah, bh, acc[nt], 0, 0, 0);
      acc[nt] = __builtin_amdgcn_mfma_f32_16x16x32_bf16(al, bh, acc[nt], 0, 0, 0);
      acc[nt] = __builtin_amdgcn_mfma_f32_16x16x32_bf16(ah, bl, acc[nt], 0, 0, 0);
    }
  }
  __syncthreads();
  float* rep = (float*)lds;  // [32][68]
  #pragma unroll
  for (int nt = 0; nt < 2; ++nt)
    #pragma unroll
    for (int i = 0; i < 4; ++i)
      rep[(wm * 16 + kg * 4 + i) * 68 + wn * 32 + nt * 16 + lm] = acc[nt][i];
  __syncthreads();
  #pragma unroll
  for (int it = 0; it < 2; ++it) {
    int slot = t + it * 256;
    int lrow = slot >> 4;
    int q = slot & 15;
    int gr = bm + lrow;
    if (gr < Mpad) {
      float dn = (gr < Mreal) ? dinv[gr] : 0.f;
      const float* rp = rep + lrow * 68 + q * 4;
      int f0 = bn + q * 4;
      int sel = f0 >> 5;  // slice
      uint2 o = make_uint2(packbf(rp[0] * dn, rp[1] * dn),
                           packbf(rp[2] * dn, rp[3] * dn));
      *(uint2*)(T + (size_t)sel * Mpad * 32 + (size_t)gr * 32 + (f0 & 31)) = o;
    }
  }
}

// ---------------- Sliced aggregation v4 ------------------------------------
// 16-lane group per node (4 nodes/wave); within group: 4 edge sub-slots (es)
// x 4 lanes (fl, 16B each) covering the 64B slice row. 16 edges/group-iter,
// 4 outstanding gathers/lane, index prefetch, dummy-row-N predication.
template <int NSL, int NC, bool RELU>
__global__ __launch_bounds__(256) void k_agg_v4(
    const unsigned short* __restrict__ T, const int* __restrict__ csr,
    const int* __restrict__ offs, const int* __restrict__ deg,
    const float* __restrict__ dinv, const float* __restrict__ bias,
    float* __restrict__ Out, int N, int Mpad) {
  const int lane = threadIdx.x & 63;
  const int wave = threadIdx.x >> 6;
  const int P = blockIdx.x;
  const int xcd = P & 7;
  const int slice = xcd & (NSL - 1);
  const int chunk = (P >> 3) * (8 / NSL) + (xcd / NSL);
  const int grp = lane >> 4;       // node group within wave (4 nodes/wave)
  const int es = (lane >> 2) & 3;  // edge sub-slot
  const int fl = lane & 3;         // 16B piece of the 64B slice row
  const int node = chunk * 16 + wave * 4 + grp;
  const char* Tb = (const char*)(T + (size_t)slice * Mpad * 32);
  const bool valid = node < N;
  int start = 0, cnt = 0;
  if (valid) { start = offs[node]; cnt = deg[node]; }
  const unsigned loff = (unsigned)fl << 4;
  float4 lo0 = {0,0,0,0}, hi0 = {0,0,0,0}, lo1 = {0,0,0,0}, hi1 = {0,0,0,0};
  float4 lo2 = {0,0,0,0}, hi2 = {0,0,0,0}, lo3 = {0,0,0,0}, hi3 = {0,0,0,0};
  {  // self loop: only es==0 lanes add the node's own row; others hit zeros
    int s = (es == 0 && valid) ? node : N;
    uint4 v = *(const uint4*)(Tb + (((unsigned)s << 6) + loff));
    accum8(lo0, hi0, v);
  }
  int nit = (cnt + 15) >> 4;  // 0 if no edges
  int b0 = start + es;
  int r0 = csr[b0], r1 = csr[b0 + 4], r2 = csr[b0 + 8], r3 = csr[b0 + 12];
  int cs = cnt - es;  // slot k valid this iter iff k*4 < cs
  for (int it = 0; it < nit; ++it) {
    bool last = (it + 1 == nit);
    int n0, n1, n2, n3;
    if (!last) {  // prefetch next iteration's indices
      int bb = b0 + (it + 1) * 16;
      n0 = csr[bb]; n1 = csr[bb + 4]; n2 = csr[bb + 8]; n3 = csr[bb + 12];
    }
    int s0 = (0 < cs) ? r0 : N;
    int s1 = (4 < cs) ? r1 : N;
    int s2 = (8 < cs) ? r2 : N;
    int s3 = (12 < cs) ? r3 : N;
    uint4 v0 = *(const uint4*)(Tb + (((unsigned)s0 << 6) + loff));
    uint4 v1 = *(const uint4*)(Tb + (((unsigned)s1 << 6) + loff));
    uint4 v2 = *(const uint4*)(Tb + (((unsigned)s2 << 6) + loff));
    uint4 v3 = *(const uint4*)(Tb + (((unsigned)s3 << 6) + loff));
    accum8(lo0, hi0, v0); accum8(lo1, hi1, v1);
    accum8(lo2, hi2, v2); accum8(lo3, hi3, v3);
    if (!last) { r0 = n0; r1 = n1; r2 = n2; r3 = n3; cs -= 16; }
  }
  add4(lo0, lo1); add4(hi0, hi1);
  add4(lo2, lo3); add4(hi2, hi3);
  add4(lo0, lo2); add4(hi0, hi2);
  red8(lo0, hi0, 4);   // combine es slots (lane bits 2-3)
  red8(lo0, hi0, 8);
  if (es == 0 && valid) {
    float dn = dinv[node];
    int fb = slice * 32 + fl * 8;
    float4 bb0 = *(const float4*)(bias + fb);
    float4 bb1 = *(const float4*)(bias + fb + 4);
    float4 o0, o1;
    o0.x = fmaf(lo0.x, dn, bb0.x); o0.y = fmaf(lo0.y, dn, bb0.y);
    o0.z = fmaf(lo0.z, dn, bb0.z); o0.w = fmaf(lo0.w, dn, bb0.w);
    o1.x = fmaf(hi0.x, dn, bb1.x); o1.y = fmaf(hi0.y, dn, bb1.y);
    o1.z = fmaf(hi0.z, dn, bb1.z); o1.w = fmaf(hi0.w, dn, bb1.w);
    if (RELU) {
      o0.x = fmaxf(o0.x, 0.f); o0.y = fmaxf(o0.y, 0.f);
      o0.z = fmaxf(o0.z, 0.f); o0.w = fmaxf(o0.w, 0.f);
      o1.x = fmaxf(o1.x, 0.f); o1.y = fmaxf(o1.y, 0.f);
      o1.z = fmaxf(o1.z, 0.f); o1.w = fmaxf(o1.w, 0.f);
    }
    *(float4*)(Out + (size_t)node * NC + fb) = o0;
    *(float4*)(Out + (size_t)node * NC + fb + 4) = o1;
  }
}

extern "C" void kernel_launch(void* const* d_in, const int* in_sizes, int n_in,
                              void* d_out, int out_size, void* d_ws, size_t ws_size,
                              hipStream_t stream) {
  const float* x = (const float*)d_in[0];
  const int* ei = (const int*)d_in[1];
  const float* W1 = (const float*)d_in[2];
  const float* b1 = (const float*)d_in[3];
  const float* W2 = (const float*)d_in[4];
  const float* b2 = (const float*)d_in[5];
  float* out = (float*)d_out;

  const int N = in_sizes[0] / 128;  // 50000
  const int E = in_sizes[1] / 2;    // 1600000
  const int* src = ei;
  const int* dst = ei + E;

  const int NB = (N + (1 << BSH) - 1) >> BSH;  // buckets (782)
  const int NBLK = (E + CH - 1) / CH;          // partition blocks (196)
  const int M = NB * NBLK;                     // count-table entries
  const int NSB = (M + 1023) / 1024;           // scan blocks (<=256)

  // workspace layout (aliased; tables live in A region, packed pairs in B)
  float* A = (float*)d_ws;                 // N*128 floats region
  float* B = A + (size_t)N * 128;          // N*128 floats region
  int* csr = (int*)(B + (size_t)N * 128);  // E ints (+128 pad for raw prefetch)
  int* deg = csr + E + 128;                // N
  int* offs = deg + N;                     // N
  float* dinv = (float*)(offs + N);        // N
  int* cnt = (int*)A;                      // M (alias A)
  int* pos = cnt + M;                      // M (alias A)
  int* bsum = pos + M;                     // <=256 (alias A)
  int* ppack = (int*)B;                    // E packed pairs (alias B)
  unsigned short* T1 = (unsigned short*)A;  // 4 slices x Mpad x 32 bf16
  unsigned short* T2 = (unsigned short*)A;  // 2 slices x Mpad x 32 bf16

  kA_count<<<NBLK, 1024, 0, stream>>>(dst, E, NB, NBLK, cnt);
  k_scanA<<<NSB, 1024, 0, stream>>>(cnt, M, pos, bsum);
  kC_scatter<<<NBLK, 1024, 0, stream>>>(src, dst, E, NB, NBLK, NSB, pos, bsum, ppack);
  kD_build<<<NB, 256, 0, stream>>>(ppack, pos, bsum, N, E, NB, NBLK, NSB,
                                   csr, deg, offs, dinv);

  const int Mpad = N + 1;
  const int MT = (Mpad + 31) / 32;   // m-blocks (covers dummy row N)
  const int NC16 = (N + 15) / 16;    // node chunks of 16

  dim3 g1(MT, 2);
  k_gemm_mfma<<<g1, 256, 0, stream>>>(x, W1, dinv, T1, N, Mpad, 128);
  {  // layer-1 agg: 4 slices (2 XCDs each)
    int grid = 8 * ((NC16 + 1) / 2);
    k_agg_v4<4, 128, true><<<grid, 256, 0, stream>>>(T1, csr, offs, deg,
                                                     dinv, b1, B, N, Mpad);
  }
  dim3 g2(MT, 1);
  k_gemm_mfma<<<g2, 256, 0, stream>>>(B, W2, dinv, T2, N, Mpad, 64);
  {  // layer-2 agg: 2 slices (4 XCDs each)
    int grid = 8 * ((NC16 + 3) / 4);
    k_agg_v4<2, 64, false><<<grid, 256, 0, stream>>>(T2, csr, offs, deg,
                                                     dinv, b2, out, N, Mpad);
  }
}